// Round 16
// baseline (189.203 us; speedup 1.0000x reference)
//
#include <hip/hip_runtime.h>

// Cross-attention: B=8, P=512, S=2048, D_MODEL=1024, H=16, HD=64
#define DM 1024
#define B_ 8
#define P_ 512
#define S_ 2048

typedef __bf16 bf16;
typedef __bf16 bf16x4 __attribute__((ext_vector_type(4)));
typedef __bf16 bf16x8 __attribute__((ext_vector_type(8)));
typedef float f32x4 __attribute__((ext_vector_type(4)));
typedef float f32x16 __attribute__((ext_vector_type(16)));

__device__ __forceinline__ void gload_lds16(const void* g, void* l) {
  __builtin_amdgcn_global_load_lds(
      (const __attribute__((address_space(1))) unsigned int*)g,
      (__attribute__((address_space(3))) unsigned int*)l, 16, 0, 0);
}

__device__ __forceinline__ f32x4 mfma16(bf16x8 a, bf16x8 b, f32x4 c) {
  return __builtin_amdgcn_mfma_f32_16x16x32_bf16(a, b, c, 0, 0, 0);
}
__device__ __forceinline__ f32x16 mfma32(bf16x8 a, bf16x8 b, f32x16 c) {
  return __builtin_amdgcn_mfma_f32_32x32x16_bf16(a, b, c, 0, 0, 0);
}

__device__ __forceinline__ unsigned cvt_pk_bf16(float lo, float hi) {
  unsigned r;
  asm("v_cvt_pk_bf16_f32 %0, %1, %2" : "=v"(r) : "v"(lo), "v"(hi));
  return r;
}
// v_permlane32_swap_b32: new_a = {a.lo, b.lo}, new_b = {a.hi, b.hi}
__device__ __forceinline__ void plswap(unsigned& a, unsigned& b) {
  asm volatile("s_nop 1\n\tv_permlane32_swap_b32 %0, %1" : "+v"(a), "+v"(b));
}
__device__ __forceinline__ void bar() {
  asm volatile("" ::: "memory");
  __builtin_amdgcn_s_barrier();
  asm volatile("" ::: "memory");
}

union U8 { unsigned u[4]; bf16x8 v; };

// scale folded into Q projection: 1/sqrt(64) * log2(e)
#define QSCALE 0.18033688011112042f

// ---------------- fused f32 -> bf16 conversion (all 6 tensors, 1 launch) ----
__global__ void cvt_all(const float* __restrict__ ts, const float* __restrict__ llm,
                        const float* __restrict__ qw, const float* __restrict__ kw,
                        const float* __restrict__ vw, const float* __restrict__ ow,
                        bf16* __restrict__ ts_o, bf16* __restrict__ llm_o,
                        bf16* __restrict__ qw_o, bf16* __restrict__ kw_o,
                        bf16* __restrict__ vw_o, bf16* __restrict__ ow_o) {
  const int total = 24 << 18;
  int i = blockIdx.x * blockDim.x + threadIdx.x;
  const int stride = gridDim.x * blockDim.x;
  for (; i < total; i += stride) {
    int r = i >> 18;
    const float* in;
    bf16* out;
    int off;
    if (r < 4) { in = ts; out = ts_o; off = i; }
    else if (r < 20) { in = llm; out = llm_o; off = i - (4 << 18); }
    else if (r == 20) { in = qw; out = qw_o; off = i - (20 << 18); }
    else if (r == 21) { in = kw; out = kw_o; off = i - (21 << 18); }
    else if (r == 22) { in = vw; out = vw_o; off = i - (22 << 18); }
    else { in = ow; out = ow_o; off = i - (23 << 18); }
    float4 v = reinterpret_cast<const float4*>(in)[off];
    bf16x4 o;
    o[0] = (bf16)v.x; o[1] = (bf16)v.y; o[2] = (bf16)v.z; o[3] = (bf16)v.w;
    reinterpret_cast<bf16x4*>(out)[off] = o;
  }
}

enum { MODE_F32 = 0, MODE_Q = 1 };

// ---- 128x128 BT GEMM, 8 waves (2M x 4N, wave tile 64x32) for Q/O proj ------
template <int MODE>
__global__ __launch_bounds__(512) void gemm_bt(
    const bf16* __restrict__ A, const bf16* __restrict__ Bw,
    const float* __restrict__ bias, void* __restrict__ out) {
  __shared__ char As[16384];  // [128 rows][64 k * 2B]
  __shared__ char Bs[16384];
  const int tid = threadIdx.x;
  const int w = tid >> 6, lane = tid & 63;
  const int g = lane >> 4, l15 = lane & 15;
  const int tn = blockIdx.x, tm = blockIdx.y;
  const int wm = w >> 2, wn = w & 3;  // wave tile: M 64 rows x N 32 cols

  f32x4 acc[4][2] = {};

  const char* Abase = (const char*)A + (size_t)(tm * 128) * (DM * 2);
  const char* Bbase = (const char*)Bw + (size_t)(tn * 128) * (DM * 2);

  for (int kt = 0; kt < DM / 64; ++kt) {
#pragma unroll
    for (int i = 0; i < 2; ++i) {
      int f = i * 8192 + (w * 64 + lane) * 16;
      int row = f >> 7;          // 128B per row (64 bf16)
      int kb = f & 127;
      int src = kb ^ ((row & 7) << 4);
      gload_lds16(Abase + (size_t)row * (DM * 2) + kt * 128 + src,
                  As + i * 8192 + w * 1024);
      gload_lds16(Bbase + (size_t)row * (DM * 2) + kt * 128 + src,
                  Bs + i * 8192 + w * 1024);
    }
    __syncthreads();
#pragma unroll
    for (int kk = 0; kk < 2; ++kk) {
      bf16x8 af[4], bfr[2];
#pragma unroll
      for (int mi = 0; mi < 4; ++mi) {
        int row = wm * 64 + mi * 16 + l15;
        int off = row * 128 + ((kk * 64 + g * 16) ^ ((row & 7) << 4));
        af[mi] = *reinterpret_cast<const bf16x8*>(As + off);
      }
#pragma unroll
      for (int ni = 0; ni < 2; ++ni) {
        int row = wn * 32 + ni * 16 + l15;
        int off = row * 128 + ((kk * 64 + g * 16) ^ ((row & 7) << 4));
        bfr[ni] = *reinterpret_cast<const bf16x8*>(Bs + off);
      }
#pragma unroll
      for (int mi = 0; mi < 4; ++mi)
#pragma unroll
        for (int ni = 0; ni < 2; ++ni)
          acc[mi][ni] = mfma16(af[mi], bfr[ni], acc[mi][ni]);
    }
    __syncthreads();
  }

#pragma unroll
  for (int mi = 0; mi < 4; ++mi) {
#pragma unroll
    for (int ni = 0; ni < 2; ++ni) {
      const int n = tn * 128 + wn * 32 + ni * 16 + l15;
      const float bn = bias[n];
      const int mb = tm * 128 + wm * 64 + mi * 16 + g * 4;
#pragma unroll
      for (int r = 0; r < 4; ++r) {
        const int m = mb + r;
        const float v = acc[mi][ni][r] + bn;
        if constexpr (MODE == MODE_F32) {
          ((float*)out)[(size_t)m * 1024 + n] = v;
        } else {  // MODE_Q: fold softmax scale*log2e into Q
          const int b = m >> 9, p = m & 511, h = n >> 6, d = n & 63;
          ((bf16*)out)[((size_t)((b * 16 + h) * 512 + p)) * 64 + d] = (bf16)(v * QSCALE);
        }
      }
    }
  }
}

// ---- 128x128 BT GEMM, 8 waves, K+V projections fused (N=2048) --------------
// Same proven 2-barrier template as gemm_bt; 32KB LDS -> 4 blocks/CU so
// cross-block overlap hides barrier/staging stalls (vs gemm256kv's 1 block/CU).
// Grid 2048 1-D, XCD-chunked: each XCD gets 16 tm-stripes x all 16 tn ->
// A-panels (512KB each) L2-reused across the 16 tn blocks of a stripe.
__global__ __launch_bounds__(512) void gemm128kv(
    const bf16* __restrict__ A, const bf16* __restrict__ Bw,
    const float* __restrict__ kb, const float* __restrict__ vb,
    bf16* __restrict__ Kout, bf16* __restrict__ VTout) {
  __shared__ char As[16384];
  __shared__ char Bs[16384];
  const int tid = threadIdx.x;
  const int w = tid >> 6, lane = tid & 63;
  const int g = lane >> 4, l15 = lane & 15;
  const int wm = w >> 2, wn = w & 3;

  // bijective XCD-chunk swizzle: 2048 blocks, 8 XCDs, 256 each
  const int id = blockIdx.x;
  const int nid = (id & 7) * 256 + (id >> 3);
  const int tm = nid >> 4, tn = nid & 15;

  f32x4 acc[4][2] = {};

  const char* Abase = (const char*)A + (size_t)(tm * 128) * (DM * 2);
  const char* Bbase = (const char*)Bw + (size_t)(tn * 128) * (DM * 2);

  for (int kt = 0; kt < DM / 64; ++kt) {
#pragma unroll
    for (int i = 0; i < 2; ++i) {
      int f = i * 8192 + (w * 64 + lane) * 16;
      int row = f >> 7;
      int kb2 = f & 127;
      int src = kb2 ^ ((row & 7) << 4);
      gload_lds16(Abase + (size_t)row * (DM * 2) + kt * 128 + src,
                  As + i * 8192 + w * 1024);
      gload_lds16(Bbase + (size_t)row * (DM * 2) + kt * 128 + src,
                  Bs + i * 8192 + w * 1024);
    }
    __syncthreads();
#pragma unroll
    for (int kk = 0; kk < 2; ++kk) {
      bf16x8 af[4], bfr[2];
#pragma unroll
      for (int mi = 0; mi < 4; ++mi) {
        int row = wm * 64 + mi * 16 + l15;
        int off = row * 128 + ((kk * 64 + g * 16) ^ ((row & 7) << 4));
        af[mi] = *reinterpret_cast<const bf16x8*>(As + off);
      }
#pragma unroll
      for (int ni = 0; ni < 2; ++ni) {
        int row = wn * 32 + ni * 16 + l15;
        int off = row * 128 + ((kk * 64 + g * 16) ^ ((row & 7) << 4));
        bfr[ni] = *reinterpret_cast<const bf16x8*>(Bs + off);
      }
#pragma unroll
      for (int mi = 0; mi < 4; ++mi)
#pragma unroll
        for (int ni = 0; ni < 2; ++ni)
          acc[mi][ni] = mfma16(af[mi], bfr[ni], acc[mi][ni]);
    }
    __syncthreads();
  }

  // epilogue: n in [0,2048); n<1024 -> K [B][H][S][64]; else VT [B][H][64][S]
#pragma unroll
  for (int mi = 0; mi < 4; ++mi) {
#pragma unroll
    for (int ni = 0; ni < 2; ++ni) {
      const int n = tn * 128 + wn * 32 + ni * 16 + l15;
      const int mb = tm * 128 + wm * 64 + mi * 16 + g * 4;
      const int b = mb >> 11, s = mb & 2047;
      if (n >= 1024) {  // VT: rows r = consecutive s -> packed bf16x4 store
        const int h = (n - 1024) >> 6, d = (n - 1024) & 63;
        const float bn = vb[n - 1024];
        bf16x4 pk;
#pragma unroll
        for (int r = 0; r < 4; ++r) pk[r] = (bf16)(acc[mi][ni][r] + bn);
        *reinterpret_cast<bf16x4*>(VTout + ((size_t)((b * 16 + h) * 64 + d)) * 2048 + s) = pk;
      } else {  // K
        const int h = n >> 6, d = n & 63;
        const float bn = kb[n];
#pragma unroll
        for (int r = 0; r < 4; ++r)
          Kout[((size_t)((b * 16 + h) * 2048 + s + r)) * 64 + d] =
              (bf16)(acc[mi][ni][r] + bn);
      }
    }
  }
}

// ---------------- Flash attention: chunk=128, proven sync skeleton ----------
// STAGE(c+1) -> counted vmcnt -> bar -> compute (two 64-kv sub-tiles) -> bar.
// LDS: 2 x (16KB K[128][128B] + 16KB V[64][256B]) = 64KB; 2 blocks/CU.
__global__ __launch_bounds__(256) void attn_kernel(
    const bf16* __restrict__ Q, const bf16* __restrict__ K,
    const bf16* __restrict__ VT, bf16* __restrict__ ctx) {
  __shared__ char lds[65536];
  const int tid = threadIdx.x;
  const int w = tid >> 6, lane = tid & 63;
  const int l31 = lane & 31, hi = lane >> 5;

  const int n = blockIdx.x;
  const int xcd = n & 7, mm = n >> 3;
  const int bh = xcd + ((mm >> 2) << 3);
  const int qt = mm & 3;
  const int q0 = qt * 128;

  const char* Kb = (const char*)(K + (size_t)bh * 2048 * 64);
  const char* Vb = (const char*)(VT + (size_t)bh * 64 * 2048);

  const char* Qrow = (const char*)(Q + ((size_t)bh * 512 + q0 + w * 32 + l31) * 64);
  bf16x8 qf[4];
#pragma unroll
  for (int kk = 0; kk < 4; ++kk)
    qf[kk] = *reinterpret_cast<const bf16x8*>(Qrow + kk * 32 + hi * 16);

  float lrun = 0.f;
  f32x16 oacc[2] = {};

#define STAGE(S0, BUF)                                                        \
  {                                                                           \
    _Pragma("unroll") for (int i = 0; i < 4; ++i) {                           \
      int f = i * 4096 + (w * 64 + lane) * 16;                                \
      int krow = f >> 7, kbyte = f & 127;                                     \
      gload_lds16(Kb + (size_t)((S0) + krow) * 128 +                          \
                      (kbyte ^ ((krow & 7) << 4)),                            \
                  (BUF) + i * 4096 + w * 1024);                               \
      int vrow = f >> 8, vbyte = f & 255;                                     \
      gload_lds16(Vb + (size_t)vrow * 4096 + (size_t)(S0) * 2 +               \
                      (vbyte ^ ((vrow & 7) << 4)),                            \
                  (BUF) + 16384 + i * 4096 + w * 1024);                       \
    }                                                                         \
  }

#define SUBTILE(T2, CUR)                                                      \
  {                                                                           \
    f32x16 sa[2] = {};                                                        \
    __builtin_amdgcn_s_setprio(1);                                            \
    _Pragma("unroll") for (int t = 0; t < 2; ++t) {                           \
      _Pragma("unroll") for (int kk = 0; kk < 4; ++kk) {                      \
        int row = (T2) * 64 + t * 32 + l31;                                   \
        int off = row * 128 + ((kk * 32 + hi * 16) ^ ((row & 7) << 4));       \
        bf16x8 kf = *reinterpret_cast<const bf16x8*>((CUR) + off);            \
        sa[t] = mfma32(kf, qf[kk], sa[t]);                                    \
      }                                                                       \
    }                                                                         \
    __builtin_amdgcn_s_setprio(0);                                            \
    bf16x8 vf[8];                                                             \
    _Pragma("unroll") for (int dt = 0; dt < 2; ++dt)                          \
        _Pragma("unroll") for (int ks = 0; ks < 4; ++ks) {                    \
      int row = dt * 32 + l31;                                                \
      int col = (T2) * 128 + ks * 32 + hi * 16;                               \
      int off = 16384 + row * 256 + (col ^ ((row & 7) << 4));                 \
      vf[dt * 4 + ks] = *reinterpret_cast<const bf16x8*>((CUR) + off);        \
    }                                                                         \
    bf16x8 pf[4];                                                             \
    _Pragma("unroll") for (int t = 0; t < 2; ++t)                             \
        _Pragma("unroll") for (int h2 = 0; h2 < 2; ++h2) {                    \
      float p[8];                                                             \
      _Pragma("unroll") for (int j = 0; j < 8; ++j) {                         \
        p[j] = __builtin_amdgcn_exp2f(sa[t][8 * h2 + j]);                     \
        lrun += p[j];                                                         \
      }                                                                       \
      unsigned a0 = cvt_pk_bf16(p[0], p[1]);                                  \
      unsigned a1 = cvt_pk_bf16(p[2], p[3]);                                  \
      unsigned a2 = cvt_pk_bf16(p[4], p[5]);                                  \
      unsigned a3 = cvt_pk_bf16(p[6], p[7]);                                  \
      plswap(a0, a2);                                                         \
      plswap(a1, a3);                                                         \
      U8 u;                                                                   \
      u.u[0] = a0; u.u[1] = a1; u.u[2] = a2; u.u[3] = a3;                     \
      pf[t * 2 + h2] = u.v;                                                   \
    }                                                                         \
    __builtin_amdgcn_s_setprio(1);                                            \
    _Pragma("unroll") for (int dt = 0; dt < 2; ++dt)                          \
        _Pragma("unroll") for (int ks = 0; ks < 4; ++ks)                      \
            oacc[dt] = mfma32(vf[dt * 4 + ks], pf[ks], oacc[dt]);             \
    __builtin_amdgcn_s_setprio(0);                                            \
  }

  STAGE(0, lds);

  for (int c = 0; c < 16; ++c) {
    char* cur = lds + (c & 1) * 32768;
    if (c + 1 < 16) {
      STAGE((c + 1) * 128, lds + ((c + 1) & 1) * 32768);
      asm volatile("s_waitcnt vmcnt(8)" ::: "memory");  // current tile landed
    } else {
      asm volatile("s_waitcnt vmcnt(0)" ::: "memory");
    }
    bar();

    SUBTILE(0, cur);
    SUBTILE(1, cur);

    bar();  // all waves done reading cur before restage
  }

  // epilogue: ctx[b][p][h*64 + d], d = (r&3)+8*(r>>2)+4*hi+32*dt
  lrun += __shfl_xor(lrun, 32);
  const float inv = 1.0f / lrun;
  const int b = bh >> 4, h = bh & 15;
  const int prow = q0 + w * 32 + l31;
  bf16* dst = ctx + ((size_t)(b * 512 + prow)) * 1024 + h * 64;
#pragma unroll
  for (int dt = 0; dt < 2; ++dt)
#pragma unroll
    for (int g4 = 0; g4 < 4; ++g4) {
      bf16x4 pk4;
#pragma unroll
      for (int r = 0; r < 4; ++r) pk4[r] = (bf16)(oacc[dt][g4 * 4 + r] * inv);
      *reinterpret_cast<bf16x4*>(dst + dt * 32 + g4 * 8 + hi * 4) = pk4;
    }
#undef STAGE
#undef SUBTILE
}

// ---------------- launch ----------------
extern "C" void kernel_launch(void* const* d_in, const int* in_sizes, int n_in,
                              void* d_out, int out_size, void* d_ws, size_t ws_size,
                              hipStream_t stream) {
  const float* ts = (const float*)d_in[0];
  const float* llm = (const float*)d_in[1];
  const float* qw = (const float*)d_in[2];
  const float* qb = (const float*)d_in[3];
  const float* kw = (const float*)d_in[4];
  const float* kb = (const float*)d_in[5];
  const float* vw = (const float*)d_in[6];
  const float* vb = (const float*)d_in[7];
  const float* ow = (const float*)d_in[8];
  const float* ob = (const float*)d_in[9];

  char* ws = (char*)d_ws;
  bf16* ts_bf = (bf16*)(ws + (0ull << 20));    // 8 MB
  bf16* llm_bf = (bf16*)(ws + (8ull << 20));   // 32 MB
  bf16* qw_bf = (bf16*)(ws + (40ull << 20));   // 2 MB
  bf16* kw_bf = (bf16*)(ws + (42ull << 20));   // 2 MB  } adjacent: [kw;vw]
  bf16* vw_bf = (bf16*)(ws + (44ull << 20));   // 2 MB  } = 2048x1024 concat
  bf16* ow_bf = (bf16*)(ws + (46ull << 20));   // 2 MB
  bf16* Qb = (bf16*)(ws + (48ull << 20));      // 8 MB  [B,H,P,64] (pre-scaled)
  bf16* Kb = (bf16*)(ws + (56ull << 20));      // 32 MB [B,H,S,64]
  bf16* VTb = (bf16*)(ws + (88ull << 20));     // 32 MB [B,H,64,S]
  bf16* ctx = (bf16*)(ws + (120ull << 20));    // 8 MB  [B,P,1024]

  cvt_all<<<2048, 256, 0, stream>>>(ts, llm, qw, kw, vw, ow,
                                    ts_bf, llm_bf, qw_bf, kw_bf, vw_bf, ow_bf);

  gemm_bt<MODE_Q><<<dim3(8, 32), 512, 0, stream>>>(ts_bf, qw_bf, qb, Qb);
  gemm128kv<<<2048, 512, 0, stream>>>(llm_bf, kw_bf, kb, vb, Kb, VTb);
  attn_kernel<<<512, 256, 0, stream>>>(Qb, Kb, VTb, ctx);
  gemm_bt<MODE_F32><<<dim3(8, 32), 512, 0, stream>>>(ctx, ow_bf, ob, (void*)d_out);
}

// Round 17
// 188.016 us; speedup vs baseline: 1.0063x; 1.0063x over previous
//
#include <hip/hip_runtime.h>

// Cross-attention: B=8, P=512, S=2048, D_MODEL=1024, H=16, HD=64
#define DM 1024
#define B_ 8
#define P_ 512
#define S_ 2048

typedef __bf16 bf16;
typedef __bf16 bf16x4 __attribute__((ext_vector_type(4)));
typedef __bf16 bf16x8 __attribute__((ext_vector_type(8)));
typedef float f32x4 __attribute__((ext_vector_type(4)));
typedef float f32x16 __attribute__((ext_vector_type(16)));

__device__ __forceinline__ void gload_lds16(const void* g, void* l) {
  __builtin_amdgcn_global_load_lds(
      (const __attribute__((address_space(1))) unsigned int*)g,
      (__attribute__((address_space(3))) unsigned int*)l, 16, 0, 0);
}

__device__ __forceinline__ f32x4 mfma16(bf16x8 a, bf16x8 b, f32x4 c) {
  return __builtin_amdgcn_mfma_f32_16x16x32_bf16(a, b, c, 0, 0, 0);
}
__device__ __forceinline__ f32x16 mfma32(bf16x8 a, bf16x8 b, f32x16 c) {
  return __builtin_amdgcn_mfma_f32_32x32x16_bf16(a, b, c, 0, 0, 0);
}

__device__ __forceinline__ unsigned cvt_pk_bf16(float lo, float hi) {
  unsigned r;
  asm("v_cvt_pk_bf16_f32 %0, %1, %2" : "=v"(r) : "v"(lo), "v"(hi));
  return r;
}
// v_permlane32_swap_b32: new_a = {a.lo, b.lo}, new_b = {a.hi, b.hi}
__device__ __forceinline__ void plswap(unsigned& a, unsigned& b) {
  asm volatile("s_nop 1\n\tv_permlane32_swap_b32 %0, %1" : "+v"(a), "+v"(b));
}
__device__ __forceinline__ void bar() {
  asm volatile("" ::: "memory");
  __builtin_amdgcn_s_barrier();
  asm volatile("" ::: "memory");
}

union U8 { unsigned u[4]; bf16x8 v; };

// scale folded into Q projection: 1/sqrt(64) * log2(e)
#define QSCALE 0.18033688011112042f

// ---------------- fused f32 -> bf16 conversion (all 6 tensors, 1 launch) ----
__global__ void cvt_all(const float* __restrict__ ts, const float* __restrict__ llm,
                        const float* __restrict__ qw, const float* __restrict__ kw,
                        const float* __restrict__ vw, const float* __restrict__ ow,
                        bf16* __restrict__ ts_o, bf16* __restrict__ llm_o,
                        bf16* __restrict__ qw_o, bf16* __restrict__ kw_o,
                        bf16* __restrict__ vw_o, bf16* __restrict__ ow_o) {
  const int total = 24 << 18;
  int i = blockIdx.x * blockDim.x + threadIdx.x;
  const int stride = gridDim.x * blockDim.x;
  for (; i < total; i += stride) {
    int r = i >> 18;
    const float* in;
    bf16* out;
    int off;
    if (r < 4) { in = ts; out = ts_o; off = i; }
    else if (r < 20) { in = llm; out = llm_o; off = i - (4 << 18); }
    else if (r == 20) { in = qw; out = qw_o; off = i - (20 << 18); }
    else if (r == 21) { in = kw; out = kw_o; off = i - (21 << 18); }
    else if (r == 22) { in = vw; out = vw_o; off = i - (22 << 18); }
    else { in = ow; out = ow_o; off = i - (23 << 18); }
    float4 v = reinterpret_cast<const float4*>(in)[off];
    bf16x4 o;
    o[0] = (bf16)v.x; o[1] = (bf16)v.y; o[2] = (bf16)v.z; o[3] = (bf16)v.w;
    reinterpret_cast<bf16x4*>(out)[off] = o;
  }
}

enum { MODE_F32 = 0, MODE_Q = 1 };

// ---- 128x128 BT GEMM, 8 waves (2M x 4N, wave tile 64x32) for Q/O proj ------
template <int MODE>
__global__ __launch_bounds__(512) void gemm_bt(
    const bf16* __restrict__ A, const bf16* __restrict__ Bw,
    const float* __restrict__ bias, void* __restrict__ out) {
  __shared__ char As[16384];  // [128 rows][64 k * 2B]
  __shared__ char Bs[16384];
  const int tid = threadIdx.x;
  const int w = tid >> 6, lane = tid & 63;
  const int g = lane >> 4, l15 = lane & 15;
  const int tn = blockIdx.x, tm = blockIdx.y;
  const int wm = w >> 2, wn = w & 3;  // wave tile: M 64 rows x N 32 cols

  f32x4 acc[4][2] = {};

  const char* Abase = (const char*)A + (size_t)(tm * 128) * (DM * 2);
  const char* Bbase = (const char*)Bw + (size_t)(tn * 128) * (DM * 2);

  for (int kt = 0; kt < DM / 64; ++kt) {
#pragma unroll
    for (int i = 0; i < 2; ++i) {
      int f = i * 8192 + (w * 64 + lane) * 16;
      int row = f >> 7;          // 128B per row (64 bf16)
      int kb = f & 127;
      int src = kb ^ ((row & 7) << 4);
      gload_lds16(Abase + (size_t)row * (DM * 2) + kt * 128 + src,
                  As + i * 8192 + w * 1024);
      gload_lds16(Bbase + (size_t)row * (DM * 2) + kt * 128 + src,
                  Bs + i * 8192 + w * 1024);
    }
    __syncthreads();
#pragma unroll
    for (int kk = 0; kk < 2; ++kk) {
      bf16x8 af[4], bfr[2];
#pragma unroll
      for (int mi = 0; mi < 4; ++mi) {
        int row = wm * 64 + mi * 16 + l15;
        int off = row * 128 + ((kk * 64 + g * 16) ^ ((row & 7) << 4));
        af[mi] = *reinterpret_cast<const bf16x8*>(As + off);
      }
#pragma unroll
      for (int ni = 0; ni < 2; ++ni) {
        int row = wn * 32 + ni * 16 + l15;
        int off = row * 128 + ((kk * 64 + g * 16) ^ ((row & 7) << 4));
        bfr[ni] = *reinterpret_cast<const bf16x8*>(Bs + off);
      }
#pragma unroll
      for (int mi = 0; mi < 4; ++mi)
#pragma unroll
        for (int ni = 0; ni < 2; ++ni)
          acc[mi][ni] = mfma16(af[mi], bfr[ni], acc[mi][ni]);
    }
    __syncthreads();
  }

#pragma unroll
  for (int mi = 0; mi < 4; ++mi) {
#pragma unroll
    for (int ni = 0; ni < 2; ++ni) {
      const int n = tn * 128 + wn * 32 + ni * 16 + l15;
      const float bn = bias[n];
      const int mb = tm * 128 + wm * 64 + mi * 16 + g * 4;
#pragma unroll
      for (int r = 0; r < 4; ++r) {
        const int m = mb + r;
        const float v = acc[mi][ni][r] + bn;
        if constexpr (MODE == MODE_F32) {
          ((float*)out)[(size_t)m * 1024 + n] = v;
        } else {  // MODE_Q: fold softmax scale*log2e into Q
          const int b = m >> 9, p = m & 511, h = n >> 6, d = n & 63;
          ((bf16*)out)[((size_t)((b * 16 + h) * 512 + p)) * 64 + d] = (bf16)(v * QSCALE);
        }
      }
    }
  }
}

// ---- 128x128 BT GEMM, 8 waves, K+V projections fused (N=2048) --------------
// 32KB LDS -> 4 blocks/CU; cross-block overlap hides barrier/staging stalls.
// Grid 2048 1-D, XCD-chunked bijective swizzle (256 blocks per XCD).
__global__ __launch_bounds__(512) void gemm128kv(
    const bf16* __restrict__ A, const bf16* __restrict__ Bw,
    const float* __restrict__ kb, const float* __restrict__ vb,
    bf16* __restrict__ Kout, bf16* __restrict__ VTout) {
  __shared__ char As[16384];
  __shared__ char Bs[16384];
  const int tid = threadIdx.x;
  const int w = tid >> 6, lane = tid & 63;
  const int g = lane >> 4, l15 = lane & 15;
  const int wm = w >> 2, wn = w & 3;

  const int id = blockIdx.x;
  const int nid = (id & 7) * 256 + (id >> 3);
  const int tm = nid >> 4, tn = nid & 15;

  f32x4 acc[4][2] = {};

  const char* Abase = (const char*)A + (size_t)(tm * 128) * (DM * 2);
  const char* Bbase = (const char*)Bw + (size_t)(tn * 128) * (DM * 2);

  for (int kt = 0; kt < DM / 64; ++kt) {
#pragma unroll
    for (int i = 0; i < 2; ++i) {
      int f = i * 8192 + (w * 64 + lane) * 16;
      int row = f >> 7;
      int kb2 = f & 127;
      int src = kb2 ^ ((row & 7) << 4);
      gload_lds16(Abase + (size_t)row * (DM * 2) + kt * 128 + src,
                  As + i * 8192 + w * 1024);
      gload_lds16(Bbase + (size_t)row * (DM * 2) + kt * 128 + src,
                  Bs + i * 8192 + w * 1024);
    }
    __syncthreads();
#pragma unroll
    for (int kk = 0; kk < 2; ++kk) {
      bf16x8 af[4], bfr[2];
#pragma unroll
      for (int mi = 0; mi < 4; ++mi) {
        int row = wm * 64 + mi * 16 + l15;
        int off = row * 128 + ((kk * 64 + g * 16) ^ ((row & 7) << 4));
        af[mi] = *reinterpret_cast<const bf16x8*>(As + off);
      }
#pragma unroll
      for (int ni = 0; ni < 2; ++ni) {
        int row = wn * 32 + ni * 16 + l15;
        int off = row * 128 + ((kk * 64 + g * 16) ^ ((row & 7) << 4));
        bfr[ni] = *reinterpret_cast<const bf16x8*>(Bs + off);
      }
#pragma unroll
      for (int mi = 0; mi < 4; ++mi)
#pragma unroll
        for (int ni = 0; ni < 2; ++ni)
          acc[mi][ni] = mfma16(af[mi], bfr[ni], acc[mi][ni]);
    }
    __syncthreads();
  }

  // epilogue: n in [0,2048); n<1024 -> K [B][H][S][64]; else VT [B][H][64][S]
#pragma unroll
  for (int mi = 0; mi < 4; ++mi) {
#pragma unroll
    for (int ni = 0; ni < 2; ++ni) {
      const int n = tn * 128 + wn * 32 + ni * 16 + l15;
      const int mb = tm * 128 + wm * 64 + mi * 16 + g * 4;
      const int b = mb >> 11, s = mb & 2047;
      if (n >= 1024) {  // VT: rows r = consecutive s -> packed bf16x4 store
        const int h = (n - 1024) >> 6, d = (n - 1024) & 63;
        const float bn = vb[n - 1024];
        bf16x4 pk;
#pragma unroll
        for (int r = 0; r < 4; ++r) pk[r] = (bf16)(acc[mi][ni][r] + bn);
        *reinterpret_cast<bf16x4*>(VTout + ((size_t)((b * 16 + h) * 64 + d)) * 2048 + s) = pk;
      } else {  // K
        const int h = n >> 6, d = n & 63;
        const float bn = kb[n];
#pragma unroll
        for (int r = 0; r < 4; ++r)
          Kout[((size_t)((b * 16 + h) * 2048 + s + r)) * 64 + d] =
              (bf16)(acc[mi][ni][r] + bn);
      }
    }
  }
}

// ---------------- Flash attention: chunk=128, proven sync skeleton ----------
// STAGE(c+1) -> counted vmcnt -> bar -> compute (two 64-kv sub-tiles) -> bar.
// LDS: 2 x (16KB K[128][128B] + 16KB V[64][256B]) = 64KB; 2 blocks/CU.
__global__ __launch_bounds__(256) void attn_kernel(
    const bf16* __restrict__ Q, const bf16* __restrict__ K,
    const bf16* __restrict__ VT, bf16* __restrict__ ctx) {
  __shared__ char lds[65536];
  const int tid = threadIdx.x;
  const int w = tid >> 6, lane = tid & 63;
  const int l31 = lane & 31, hi = lane >> 5;

  const int n = blockIdx.x;
  const int xcd = n & 7, mm = n >> 3;
  const int bh = xcd + ((mm >> 2) << 3);
  const int qt = mm & 3;
  const int q0 = qt * 128;

  const char* Kb = (const char*)(K + (size_t)bh * 2048 * 64);
  const char* Vb = (const char*)(VT + (size_t)bh * 64 * 2048);

  const char* Qrow = (const char*)(Q + ((size_t)bh * 512 + q0 + w * 32 + l31) * 64);
  bf16x8 qf[4];
#pragma unroll
  for (int kk = 0; kk < 4; ++kk)
    qf[kk] = *reinterpret_cast<const bf16x8*>(Qrow + kk * 32 + hi * 16);

  float lrun = 0.f;
  f32x16 oacc[2] = {};

#define STAGE(S0, BUF)                                                        \
  {                                                                           \
    _Pragma("unroll") for (int i = 0; i < 4; ++i) {                           \
      int f = i * 4096 + (w * 64 + lane) * 16;                                \
      int krow = f >> 7, kbyte = f & 127;                                     \
      gload_lds16(Kb + (size_t)((S0) + krow) * 128 +                          \
                      (kbyte ^ ((krow & 7) << 4)),                            \
                  (BUF) + i * 4096 + w * 1024);                               \
      int vrow = f >> 8, vbyte = f & 255;                                     \
      gload_lds16(Vb + (size_t)vrow * 4096 + (size_t)(S0) * 2 +               \
                      (vbyte ^ ((vrow & 7) << 4)),                            \
                  (BUF) + 16384 + i * 4096 + w * 1024);                       \
    }                                                                         \
  }

#define SUBTILE(T2, CUR)                                                      \
  {                                                                           \
    f32x16 sa[2] = {};                                                        \
    __builtin_amdgcn_s_setprio(1);                                            \
    _Pragma("unroll") for (int t = 0; t < 2; ++t) {                           \
      _Pragma("unroll") for (int kk = 0; kk < 4; ++kk) {                      \
        int row = (T2) * 64 + t * 32 + l31;                                   \
        int off = row * 128 + ((kk * 32 + hi * 16) ^ ((row & 7) << 4));       \
        bf16x8 kf = *reinterpret_cast<const bf16x8*>((CUR) + off);            \
        sa[t] = mfma32(kf, qf[kk], sa[t]);                                    \
      }                                                                       \
    }                                                                         \
    __builtin_amdgcn_s_setprio(0);                                            \
    bf16x8 vf[8];                                                             \
    _Pragma("unroll") for (int dt = 0; dt < 2; ++dt)                          \
        _Pragma("unroll") for (int ks = 0; ks < 4; ++ks) {                    \
      int row = dt * 32 + l31;                                                \
      int col = (T2) * 128 + ks * 32 + hi * 16;                               \
      int off = 16384 + row * 256 + (col ^ ((row & 7) << 4));                 \
      vf[dt * 4 + ks] = *reinterpret_cast<const bf16x8*>((CUR) + off);        \
    }                                                                         \
    bf16x8 pf[4];                                                             \
    _Pragma("unroll") for (int t = 0; t < 2; ++t)                             \
        _Pragma("unroll") for (int h2 = 0; h2 < 2; ++h2) {                    \
      float p[8];                                                             \
      _Pragma("unroll") for (int j = 0; j < 8; ++j) {                         \
        p[j] = __builtin_amdgcn_exp2f(sa[t][8 * h2 + j]);                     \
        lrun += p[j];                                                         \
      }                                                                       \
      unsigned a0 = cvt_pk_bf16(p[0], p[1]);                                  \
      unsigned a1 = cvt_pk_bf16(p[2], p[3]);                                  \
      unsigned a2 = cvt_pk_bf16(p[4], p[5]);                                  \
      unsigned a3 = cvt_pk_bf16(p[6], p[7]);                                  \
      plswap(a0, a2);                                                         \
      plswap(a1, a3);                                                         \
      U8 u;                                                                   \
      u.u[0] = a0; u.u[1] = a1; u.u[2] = a2; u.u[3] = a3;                     \
      pf[t * 2 + h2] = u.v;                                                   \
    }                                                                         \
    __builtin_amdgcn_s_setprio(1);                                            \
    _Pragma("unroll") for (int dt = 0; dt < 2; ++dt)                          \
        _Pragma("unroll") for (int ks = 0; ks < 4; ++ks)                      \
            oacc[dt] = mfma32(vf[dt * 4 + ks], pf[ks], oacc[dt]);             \
    __builtin_amdgcn_s_setprio(0);                                            \
  }

  STAGE(0, lds);

  for (int c = 0; c < 16; ++c) {
    char* cur = lds + (c & 1) * 32768;
    if (c + 1 < 16) {
      STAGE((c + 1) * 128, lds + ((c + 1) & 1) * 32768);
      asm volatile("s_waitcnt vmcnt(8)" ::: "memory");  // current tile landed
    } else {
      asm volatile("s_waitcnt vmcnt(0)" ::: "memory");
    }
    bar();

    SUBTILE(0, cur);
    SUBTILE(1, cur);

    bar();  // all waves done reading cur before restage
  }

  // epilogue: ctx[b][p][h*64 + d], d = (r&3)+8*(r>>2)+4*hi+32*dt
  lrun += __shfl_xor(lrun, 32);
  const float inv = 1.0f / lrun;
  const int b = bh >> 4, h = bh & 15;
  const int prow = q0 + w * 32 + l31;
  bf16* dst = ctx + ((size_t)(b * 512 + prow)) * 1024 + h * 64;
#pragma unroll
  for (int dt = 0; dt < 2; ++dt)
#pragma unroll
    for (int g4 = 0; g4 < 4; ++g4) {
      bf16x4 pk4;
#pragma unroll
      for (int r = 0; r < 4; ++r) pk4[r] = (bf16)(oacc[dt][g4 * 4 + r] * inv);
      *reinterpret_cast<bf16x4*>(dst + dt * 32 + g4 * 8 + hi * 4) = pk4;
    }
#undef STAGE
#undef SUBTILE
}

// ---------------- launch ----------------
extern "C" void kernel_launch(void* const* d_in, const int* in_sizes, int n_in,
                              void* d_out, int out_size, void* d_ws, size_t ws_size,
                              hipStream_t stream) {
  const float* ts = (const float*)d_in[0];
  const float* llm = (const float*)d_in[1];
  const float* qw = (const float*)d_in[2];
  const float* qb = (const float*)d_in[3];
  const float* kw = (const float*)d_in[4];
  const float* kb = (const float*)d_in[5];
  const float* vw = (const float*)d_in[6];
  const float* vb = (const float*)d_in[7];
  const float* ow = (const float*)d_in[8];
  const float* ob = (const float*)d_in[9];

  char* ws = (char*)d_ws;
  bf16* ts_bf = (bf16*)(ws + (0ull << 20));    // 8 MB
  bf16* llm_bf = (bf16*)(ws + (8ull << 20));   // 32 MB
  bf16* qw_bf = (bf16*)(ws + (40ull << 20));   // 2 MB
  bf16* kw_bf = (bf16*)(ws + (42ull << 20));   // 2 MB  } adjacent: [kw;vw]
  bf16* vw_bf = (bf16*)(ws + (44ull << 20));   // 2 MB  } = 2048x1024 concat
  bf16* ow_bf = (bf16*)(ws + (46ull << 20));   // 2 MB
  bf16* Qb = (bf16*)(ws + (48ull << 20));      // 8 MB  [B,H,P,64] (pre-scaled)
  bf16* Kb = (bf16*)(ws + (56ull << 20));      // 32 MB [B,H,S,64]
  bf16* VTb = (bf16*)(ws + (88ull << 20));     // 32 MB [B,H,64,S]
  bf16* ctx = (bf16*)(ws + (120ull << 20));    // 8 MB  [B,P,1024]

  cvt_all<<<2048, 256, 0, stream>>>(ts, llm, qw, kw, vw, ow,
                                    ts_bf, llm_bf, qw_bf, kw_bf, vw_bf, ow_bf);

  gemm128kv<<<2048, 512, 0, stream>>>(llm_bf, kw_bf, kb, vb, Kb, VTb);
  gemm_bt<MODE_Q><<<dim3(8, 32), 512, 0, stream>>>(ts_bf, qw_bf, qb, Qb);
  attn_kernel<<<512, 256, 0, stream>>>(Qb, Kb, VTb, ctx);
  gemm_bt<MODE_F32><<<dim3(8, 32), 512, 0, stream>>>(ctx, ow_bf, ob, (void*)d_out);
}

// Round 18
// 182.287 us; speedup vs baseline: 1.0379x; 1.0314x over previous
//
#include <hip/hip_runtime.h>

// Cross-attention: B=8, P=512, S=2048, D_MODEL=1024, H=16, HD=64
#define DM 1024
#define B_ 8
#define P_ 512
#define S_ 2048

typedef __bf16 bf16;
typedef __bf16 bf16x4 __attribute__((ext_vector_type(4)));
typedef __bf16 bf16x8 __attribute__((ext_vector_type(8)));
typedef float f32x4 __attribute__((ext_vector_type(4)));
typedef float f32x16 __attribute__((ext_vector_type(16)));

__device__ __forceinline__ void gload_lds16(const void* g, void* l) {
  __builtin_amdgcn_global_load_lds(
      (const __attribute__((address_space(1))) unsigned int*)g,
      (__attribute__((address_space(3))) unsigned int*)l, 16, 0, 0);
}

__device__ __forceinline__ f32x4 mfma16(bf16x8 a, bf16x8 b, f32x4 c) {
  return __builtin_amdgcn_mfma_f32_16x16x32_bf16(a, b, c, 0, 0, 0);
}
__device__ __forceinline__ f32x16 mfma32(bf16x8 a, bf16x8 b, f32x16 c) {
  return __builtin_amdgcn_mfma_f32_32x32x16_bf16(a, b, c, 0, 0, 0);
}

__device__ __forceinline__ unsigned cvt_pk_bf16(float lo, float hi) {
  unsigned r;
  asm("v_cvt_pk_bf16_f32 %0, %1, %2" : "=v"(r) : "v"(lo), "v"(hi));
  return r;
}
// v_permlane32_swap_b32: new_a = {a.lo, b.lo}, new_b = {a.hi, b.hi}
__device__ __forceinline__ void plswap(unsigned& a, unsigned& b) {
  asm volatile("s_nop 1\n\tv_permlane32_swap_b32 %0, %1" : "+v"(a), "+v"(b));
}
__device__ __forceinline__ void bar() {
  asm volatile("" ::: "memory");
  __builtin_amdgcn_s_barrier();
  asm volatile("" ::: "memory");
}

union U8 { unsigned u[4]; bf16x8 v; };

// scale folded into Q projection: 1/sqrt(64) * log2(e)
#define QSCALE 0.18033688011112042f

// ---------------- fused f32 -> bf16 conversion (all 6 tensors, 1 launch) ----
__global__ void cvt_all(const float* __restrict__ ts, const float* __restrict__ llm,
                        const float* __restrict__ qw, const float* __restrict__ kw,
                        const float* __restrict__ vw, const float* __restrict__ ow,
                        bf16* __restrict__ ts_o, bf16* __restrict__ llm_o,
                        bf16* __restrict__ qw_o, bf16* __restrict__ kw_o,
                        bf16* __restrict__ vw_o, bf16* __restrict__ ow_o) {
  const int total = 24 << 18;
  int i = blockIdx.x * blockDim.x + threadIdx.x;
  const int stride = gridDim.x * blockDim.x;
  for (; i < total; i += stride) {
    int r = i >> 18;
    const float* in;
    bf16* out;
    int off;
    if (r < 4) { in = ts; out = ts_o; off = i; }
    else if (r < 20) { in = llm; out = llm_o; off = i - (4 << 18); }
    else if (r == 20) { in = qw; out = qw_o; off = i - (20 << 18); }
    else if (r == 21) { in = kw; out = kw_o; off = i - (21 << 18); }
    else if (r == 22) { in = vw; out = vw_o; off = i - (22 << 18); }
    else { in = ow; out = ow_o; off = i - (23 << 18); }
    float4 v = reinterpret_cast<const float4*>(in)[off];
    bf16x4 o;
    o[0] = (bf16)v.x; o[1] = (bf16)v.y; o[2] = (bf16)v.z; o[3] = (bf16)v.w;
    reinterpret_cast<bf16x4*>(out)[off] = o;
  }
}

// ---- shared 8-wave 128x128 BT GEMM core (proven 2-barrier template) --------
__device__ __forceinline__ void gemm128_core(
    const char* Abase, const char* Bbase, char* As, char* Bs,
    int w, int lane, int g, int l15, int wm, int wn, f32x4 acc[4][2]) {
  for (int kt = 0; kt < DM / 64; ++kt) {
#pragma unroll
    for (int i = 0; i < 2; ++i) {
      int f = i * 8192 + (w * 64 + lane) * 16;
      int row = f >> 7;          // 128B per row (64 bf16)
      int kb2 = f & 127;
      int src = kb2 ^ ((row & 7) << 4);
      gload_lds16(Abase + (size_t)row * (DM * 2) + kt * 128 + src,
                  As + i * 8192 + w * 1024);
      gload_lds16(Bbase + (size_t)row * (DM * 2) + kt * 128 + src,
                  Bs + i * 8192 + w * 1024);
    }
    __syncthreads();
#pragma unroll
    for (int kk = 0; kk < 2; ++kk) {
      bf16x8 af[4], bfr[2];
#pragma unroll
      for (int mi = 0; mi < 4; ++mi) {
        int row = wm * 64 + mi * 16 + l15;
        int off = row * 128 + ((kk * 64 + g * 16) ^ ((row & 7) << 4));
        af[mi] = *reinterpret_cast<const bf16x8*>(As + off);
      }
#pragma unroll
      for (int ni = 0; ni < 2; ++ni) {
        int row = wn * 32 + ni * 16 + l15;
        int off = row * 128 + ((kk * 64 + g * 16) ^ ((row & 7) << 4));
        bfr[ni] = *reinterpret_cast<const bf16x8*>(Bs + off);
      }
#pragma unroll
      for (int mi = 0; mi < 4; ++mi)
#pragma unroll
        for (int ni = 0; ni < 2; ++ni)
          acc[mi][ni] = mfma16(af[mi], bfr[ni], acc[mi][ni]);
    }
    __syncthreads();
  }
}

// ---- O projection (128x128, 8 waves): ctx @ ow^T + ob -> f32 out -----------
__global__ __launch_bounds__(512) void gemm_o(
    const bf16* __restrict__ A, const bf16* __restrict__ Bw,
    const float* __restrict__ bias, float* __restrict__ out) {
  __shared__ char As[16384];
  __shared__ char Bs[16384];
  const int tid = threadIdx.x;
  const int w = tid >> 6, lane = tid & 63;
  const int g = lane >> 4, l15 = lane & 15;
  const int tn = blockIdx.x, tm = blockIdx.y;
  const int wm = w >> 2, wn = w & 3;

  f32x4 acc[4][2] = {};
  gemm128_core((const char*)A + (size_t)(tm * 128) * (DM * 2),
               (const char*)Bw + (size_t)(tn * 128) * (DM * 2),
               As, Bs, w, lane, g, l15, wm, wn, acc);

#pragma unroll
  for (int mi = 0; mi < 4; ++mi) {
#pragma unroll
    for (int ni = 0; ni < 2; ++ni) {
      const int n = tn * 128 + wn * 32 + ni * 16 + l15;
      const float bn = bias[n];
      const int mb = tm * 128 + wm * 64 + mi * 16 + g * 4;
#pragma unroll
      for (int r = 0; r < 4; ++r)
        out[(size_t)(mb + r) * 1024 + n] = acc[mi][ni][r] + bn;
    }
  }
}

// ---- grouped Q + K + V projections, one launch (2304 blocks) ---------------
// ids [0,2048): KV path (XCD-chunked swizzle, N=2048 over [kw;vw]);
// ids [2048,2304): Q path (M=4096, N=1024), backfills the KV drain tail.
// Both paths are the byte-identical proven 8-wave 128x128 core.
__global__ __launch_bounds__(512) void gemm_qkv(
    const bf16* __restrict__ llm, const bf16* __restrict__ kvw,
    const bf16* __restrict__ ts, const bf16* __restrict__ qw,
    const float* __restrict__ qb, const float* __restrict__ kb,
    const float* __restrict__ vb, bf16* __restrict__ Qout,
    bf16* __restrict__ Kout, bf16* __restrict__ VTout) {
  __shared__ char As[16384];
  __shared__ char Bs[16384];
  const int tid = threadIdx.x;
  const int w = tid >> 6, lane = tid & 63;
  const int g = lane >> 4, l15 = lane & 15;
  const int wm = w >> 2, wn = w & 3;

  const int id = blockIdx.x;
  if (id < 2048) {
    // ---------------- KV path ----------------
    const int nid = (id & 7) * 256 + (id >> 3);  // bijective XCD-chunk swizzle
    const int tm = nid >> 4, tn = nid & 15;

    f32x4 acc[4][2] = {};
    gemm128_core((const char*)llm + (size_t)(tm * 128) * (DM * 2),
                 (const char*)kvw + (size_t)(tn * 128) * (DM * 2),
                 As, Bs, w, lane, g, l15, wm, wn, acc);

#pragma unroll
    for (int mi = 0; mi < 4; ++mi) {
#pragma unroll
      for (int ni = 0; ni < 2; ++ni) {
        const int n = tn * 128 + wn * 32 + ni * 16 + l15;
        const int mb = tm * 128 + wm * 64 + mi * 16 + g * 4;
        const int b = mb >> 11, s = mb & 2047;
        if (n >= 1024) {  // VT [B][H][64][S]: rows r = consecutive s
          const int h = (n - 1024) >> 6, d = (n - 1024) & 63;
          const float bn = vb[n - 1024];
          bf16x4 pk;
#pragma unroll
          for (int r = 0; r < 4; ++r) pk[r] = (bf16)(acc[mi][ni][r] + bn);
          *reinterpret_cast<bf16x4*>(VTout + ((size_t)((b * 16 + h) * 64 + d)) * 2048 + s) = pk;
        } else {  // K [B][H][S][64]
          const int h = n >> 6, d = n & 63;
          const float bn = kb[n];
#pragma unroll
          for (int r = 0; r < 4; ++r)
            Kout[((size_t)((b * 16 + h) * 2048 + s + r)) * 64 + d] =
                (bf16)(acc[mi][ni][r] + bn);
        }
      }
    }
  } else {
    // ---------------- Q path ----------------
    const int qid = id - 2048;
    const int tn = qid & 7, tm = qid >> 3;  // N=1024 (8 tiles), M=4096 (32)

    f32x4 acc[4][2] = {};
    gemm128_core((const char*)ts + (size_t)(tm * 128) * (DM * 2),
                 (const char*)qw + (size_t)(tn * 128) * (DM * 2),
                 As, Bs, w, lane, g, l15, wm, wn, acc);

#pragma unroll
    for (int mi = 0; mi < 4; ++mi) {
#pragma unroll
      for (int ni = 0; ni < 2; ++ni) {
        const int n = tn * 128 + wn * 32 + ni * 16 + l15;
        const float bn = qb[n];
        const int mb = tm * 128 + wm * 64 + mi * 16 + g * 4;
        const int h = n >> 6, d = n & 63;
#pragma unroll
        for (int r = 0; r < 4; ++r) {
          const int m = mb + r;
          const int b = m >> 9, p = m & 511;
          Qout[((size_t)((b * 16 + h) * 512 + p)) * 64 + d] =
              (bf16)((acc[mi][ni][r] + bn) * QSCALE);
        }
      }
    }
  }
}

// ---------------- Flash attention: chunk=128, proven sync skeleton ----------
// STAGE(c+1) -> counted vmcnt -> bar -> compute (two 64-kv sub-tiles) -> bar.
// LDS: 2 x (16KB K[128][128B] + 16KB V[64][256B]) = 64KB; 2 blocks/CU.
__global__ __launch_bounds__(256) void attn_kernel(
    const bf16* __restrict__ Q, const bf16* __restrict__ K,
    const bf16* __restrict__ VT, bf16* __restrict__ ctx) {
  __shared__ char lds[65536];
  const int tid = threadIdx.x;
  const int w = tid >> 6, lane = tid & 63;
  const int l31 = lane & 31, hi = lane >> 5;

  const int n = blockIdx.x;
  const int xcd = n & 7, mm = n >> 3;
  const int bh = xcd + ((mm >> 2) << 3);
  const int qt = mm & 3;
  const int q0 = qt * 128;

  const char* Kb = (const char*)(K + (size_t)bh * 2048 * 64);
  const char* Vb = (const char*)(VT + (size_t)bh * 64 * 2048);

  const char* Qrow = (const char*)(Q + ((size_t)bh * 512 + q0 + w * 32 + l31) * 64);
  bf16x8 qf[4];
#pragma unroll
  for (int kk = 0; kk < 4; ++kk)
    qf[kk] = *reinterpret_cast<const bf16x8*>(Qrow + kk * 32 + hi * 16);

  float lrun = 0.f;
  f32x16 oacc[2] = {};

#define STAGE(S0, BUF)                                                        \
  {                                                                           \
    _Pragma("unroll") for (int i = 0; i < 4; ++i) {                           \
      int f = i * 4096 + (w * 64 + lane) * 16;                                \
      int krow = f >> 7, kbyte = f & 127;                                     \
      gload_lds16(Kb + (size_t)((S0) + krow) * 128 +                          \
                      (kbyte ^ ((krow & 7) << 4)),                            \
                  (BUF) + i * 4096 + w * 1024);                               \
      int vrow = f >> 8, vbyte = f & 255;                                     \
      gload_lds16(Vb + (size_t)vrow * 4096 + (size_t)(S0) * 2 +               \
                      (vbyte ^ ((vrow & 7) << 4)),                            \
                  (BUF) + 16384 + i * 4096 + w * 1024);                       \
    }                                                                         \
  }

#define SUBTILE(T2, CUR)                                                      \
  {                                                                           \
    f32x16 sa[2] = {};                                                        \
    __builtin_amdgcn_s_setprio(1);                                            \
    _Pragma("unroll") for (int t = 0; t < 2; ++t) {                           \
      _Pragma("unroll") for (int kk = 0; kk < 4; ++kk) {                      \
        int row = (T2) * 64 + t * 32 + l31;                                   \
        int off = row * 128 + ((kk * 32 + hi * 16) ^ ((row & 7) << 4));       \
        bf16x8 kf = *reinterpret_cast<const bf16x8*>((CUR) + off);            \
        sa[t] = mfma32(kf, qf[kk], sa[t]);                                    \
      }                                                                       \
    }                                                                         \
    __builtin_amdgcn_s_setprio(0);                                            \
    bf16x8 vf[8];                                                             \
    _Pragma("unroll") for (int dt = 0; dt < 2; ++dt)                          \
        _Pragma("unroll") for (int ks = 0; ks < 4; ++ks) {                    \
      int row = dt * 32 + l31;                                                \
      int col = (T2) * 128 + ks * 32 + hi * 16;                               \
      int off = 16384 + row * 256 + (col ^ ((row & 7) << 4));                 \
      vf[dt * 4 + ks] = *reinterpret_cast<const bf16x8*>((CUR) + off);        \
    }                                                                         \
    bf16x8 pf[4];                                                             \
    _Pragma("unroll") for (int t = 0; t < 2; ++t)                             \
        _Pragma("unroll") for (int h2 = 0; h2 < 2; ++h2) {                    \
      float p[8];                                                             \
      _Pragma("unroll") for (int j = 0; j < 8; ++j) {                         \
        p[j] = __builtin_amdgcn_exp2f(sa[t][8 * h2 + j]);                     \
        lrun += p[j];                                                         \
      }                                                                       \
      unsigned a0 = cvt_pk_bf16(p[0], p[1]);                                  \
      unsigned a1 = cvt_pk_bf16(p[2], p[3]);                                  \
      unsigned a2 = cvt_pk_bf16(p[4], p[5]);                                  \
      unsigned a3 = cvt_pk_bf16(p[6], p[7]);                                  \
      plswap(a0, a2);                                                         \
      plswap(a1, a3);                                                         \
      U8 u;                                                                   \
      u.u[0] = a0; u.u[1] = a1; u.u[2] = a2; u.u[3] = a3;                     \
      pf[t * 2 + h2] = u.v;                                                   \
    }                                                                         \
    __builtin_amdgcn_s_setprio(1);                                            \
    _Pragma("unroll") for (int dt = 0; dt < 2; ++dt)                          \
        _Pragma("unroll") for (int ks = 0; ks < 4; ++ks)                      \
            oacc[dt] = mfma32(vf[dt * 4 + ks], pf[ks], oacc[dt]);             \
    __builtin_amdgcn_s_setprio(0);                                            \
  }

  STAGE(0, lds);

  for (int c = 0; c < 16; ++c) {
    char* cur = lds + (c & 1) * 32768;
    if (c + 1 < 16) {
      STAGE((c + 1) * 128, lds + ((c + 1) & 1) * 32768);
      asm volatile("s_waitcnt vmcnt(8)" ::: "memory");  // current tile landed
    } else {
      asm volatile("s_waitcnt vmcnt(0)" ::: "memory");
    }
    bar();

    SUBTILE(0, cur);
    SUBTILE(1, cur);

    bar();  // all waves done reading cur before restage
  }

  // epilogue: ctx[b][p][h*64 + d], d = (r&3)+8*(r>>2)+4*hi+32*dt
  lrun += __shfl_xor(lrun, 32);
  const float inv = 1.0f / lrun;
  const int b = bh >> 4, h = bh & 15;
  const int prow = q0 + w * 32 + l31;
  bf16* dst = ctx + ((size_t)(b * 512 + prow)) * 1024 + h * 64;
#pragma unroll
  for (int dt = 0; dt < 2; ++dt)
#pragma unroll
    for (int g4 = 0; g4 < 4; ++g4) {
      bf16x4 pk4;
#pragma unroll
      for (int r = 0; r < 4; ++r) pk4[r] = (bf16)(oacc[dt][g4 * 4 + r] * inv);
      *reinterpret_cast<bf16x4*>(dst + dt * 32 + g4 * 8 + hi * 4) = pk4;
    }
#undef STAGE
#undef SUBTILE
}

// ---------------- launch ----------------
extern "C" void kernel_launch(void* const* d_in, const int* in_sizes, int n_in,
                              void* d_out, int out_size, void* d_ws, size_t ws_size,
                              hipStream_t stream) {
  const float* ts = (const float*)d_in[0];
  const float* llm = (const float*)d_in[1];
  const float* qw = (const float*)d_in[2];
  const float* qb = (const float*)d_in[3];
  const float* kw = (const float*)d_in[4];
  const float* kb = (const float*)d_in[5];
  const float* vw = (const float*)d_in[6];
  const float* vb = (const float*)d_in[7];
  const float* ow = (const float*)d_in[8];
  const float* ob = (const float*)d_in[9];

  char* ws = (char*)d_ws;
  bf16* ts_bf = (bf16*)(ws + (0ull << 20));    // 8 MB
  bf16* llm_bf = (bf16*)(ws + (8ull << 20));   // 32 MB
  bf16* qw_bf = (bf16*)(ws + (40ull << 20));   // 2 MB
  bf16* kw_bf = (bf16*)(ws + (42ull << 20));   // 2 MB  } adjacent: [kw;vw]
  bf16* vw_bf = (bf16*)(ws + (44ull << 20));   // 2 MB  } = 2048x1024 concat
  bf16* ow_bf = (bf16*)(ws + (46ull << 20));   // 2 MB
  bf16* Qb = (bf16*)(ws + (48ull << 20));      // 8 MB  [B,H,P,64] (pre-scaled)
  bf16* Kb = (bf16*)(ws + (56ull << 20));      // 32 MB [B,H,S,64]
  bf16* VTb = (bf16*)(ws + (88ull << 20));     // 32 MB [B,H,64,S]
  bf16* ctx = (bf16*)(ws + (120ull << 20));    // 8 MB  [B,P,1024]

  cvt_all<<<2048, 256, 0, stream>>>(ts, llm, qw, kw, vw, ow,
                                    ts_bf, llm_bf, qw_bf, kw_bf, vw_bf, ow_bf);

  gemm_qkv<<<2304, 512, 0, stream>>>(llm_bf, kw_bf, ts_bf, qw_bf,
                                     qb, kb, vb, Qb, Kb, VTb);
  attn_kernel<<<512, 256, 0, stream>>>(Qb, Kb, VTb, ctx);
  gemm_o<<<dim3(8, 32), 512, 0, stream>>>(ctx, ow_bf, ob, (float*)d_out);
}